// Round 6
// baseline (1015.591 us; speedup 1.0000x reference)
//
#include <hip/hip_runtime.h>
#include <hip/hip_bf16.h>

// B=512, T=1024, F_SEQ=64, F_TAB=128, H_SEQ=128, H_TAB=128
// 32 persistent blocks (16 batch rows each), 512 threads (8 waves).
// Wave w owns hidden units [16w,16w+16) and their 4 gate tiles (i,f,g,o).
// Weights in registers as bf16 MFMA B-fragments pre-scaled by -log2e
// (g gate by -2log2e) so sigmoid/tanh = rcp(1+exp2(y)) with no negation.
// h double-buffered in LDS (bf16, XOR-swizzled 16B blocks, no padding);
// seq staged 8 steps ahead (bf16, swizzled, packed cvt). c in fp32 regs.
// PARITY-STAGGERED PRIORITY: only even waves raise prio around the MFMA
// cluster. R2 measurement showed symmetric setprio gives zero MFMA/VALU
// overlap (MfmaUtil+VALUBusy ~= 100% serialized): both waves/SIMD raise
// prio at the same point so nothing is arbitrated. With parity stagger the
// even wave monopolizes the matrix pipe, finishes early, and runs its
// transcendental tail while the odd wave's MFMAs drain through the pipe.
// Main-loop sync is lgkmcnt-only raw s_barrier: __syncthreads would drain
// vmcnt(0) and expose the seq-prefetch HBM latency at the tt=0 barrier.
// Elementwise uses fused rcp algebra: i*g and o*tanh(c) each need one rcp.

typedef __attribute__((ext_vector_type(8))) short bf16x8;
typedef __attribute__((ext_vector_type(4))) float f32x4;
typedef __attribute__((ext_vector_type(4))) unsigned int u32x4;

#define LOG2E 1.44269504088896340736f
#define NEG2L (-2.0f * LOG2E)

__device__ __forceinline__ float fexp2(float x) {
#if __has_builtin(__builtin_amdgcn_exp2f)
    return __builtin_amdgcn_exp2f(x);
#else
    float r; asm("v_exp_f32 %0, %1" : "=v"(r) : "v"(x)); return r;
#endif
}
__device__ __forceinline__ float frcp(float x) {
#if __has_builtin(__builtin_amdgcn_rcpf)
    return __builtin_amdgcn_rcpf(x);
#else
    float r; asm("v_rcp_f32 %0, %1" : "=v"(r) : "v"(x)); return r;
#endif
}

__device__ __forceinline__ unsigned int pk_bf16(float a, float b) {
    float2 f2; f2.x = a; f2.y = b;
    __hip_bfloat162 h = __float22bfloat162_rn(f2);
    unsigned int r; __builtin_memcpy(&r, &h, 4); return r;
}
__device__ __forceinline__ short bf16b(float x) {
    __hip_bfloat16 h = __float2bfloat16(x);
    short r; __builtin_memcpy(&r, &h, 2); return r;
}

// convert 8 fp32 -> 8 bf16 and store 16B to LDS (dst 16B-aligned)
__device__ __forceinline__ void st8(short* dst, const f32x4 a, const f32x4 b) {
    u32x4 v = { pk_bf16(a[0], a[1]), pk_bf16(a[2], a[3]),
                pk_bf16(b[0], b[1]), pk_bf16(b[2], b[3]) };
    *(u32x4*)dst = v;
}

// lgkm-only block barrier: drains own LDS ops (visibility) but leaves
// global loads in flight across the barrier (no vmcnt(0) drain).
__device__ __forceinline__ void block_sync_lds() {
    asm volatile("s_waitcnt lgkmcnt(0)" ::: "memory");
    __builtin_amdgcn_s_barrier();
}

__global__ __launch_bounds__(512, 2)
void lstm_fused(const float* __restrict__ tabular,
                const float* __restrict__ seq,
                const float* __restrict__ W_ih,
                const float* __restrict__ W_hh,
                const float* __restrict__ b_ih,
                const float* __restrict__ b_hh,
                const float* __restrict__ W_tab,
                const float* __restrict__ b_tab,
                const float* __restrict__ W_out,
                const float* __restrict__ b_out,
                float* __restrict__ out)
{
    // swizzled layouts: addr(row,col) = row*STRIDE + ((col>>3 ^ (row&7))<<3) + (col&7)
    __shared__ short hbuf[2][16 * 128];      // h double buffer (bf16)
    __shared__ short sbuf[2][8 * 16 * 64];   // seq chunk double buffer (bf16)
    __shared__ float hff[16][132];           // final h (fp32)
    __shared__ float tbf[16][132];           // tab branch (fp32)

    const int tid  = threadIdx.x;
    const int lane = tid & 63;
    const int wid  = tid >> 6;       // wave 0..7
    const int l15  = lane & 15;
    const int q    = lane >> 4;      // 0..3
    const int b0   = blockIdx.x * 16;
    const int u    = wid * 16 + l15; // hidden unit 0..127
    const bool hiprio = !(wid & 1);  // even waves get the matrix pipe first

    // ---- weight fragments (bf16, pre-scaled by -s) ----
    // gate tile nt: 0=i 1=f 2=g 3=o ; gate row = nt*128 + u
    bf16x8 whh[4][4];
    bf16x8 wih[4][2];
    float  bias[4];
#pragma unroll
    for (int nt = 0; nt < 4; ++nt) {
        const int g = nt * 128 + u;
        const float s = (nt == 2) ? (-2.0f * LOG2E) : (-LOG2E);
        bias[nt] = (b_ih[g] + b_hh[g]) * s;
#pragma unroll
        for (int kc = 0; kc < 4; ++kc) {
            const float* p = W_hh + g * 128 + kc * 32 + q * 8;
            bf16x8 fr;
#pragma unroll
            for (int j = 0; j < 8; ++j) fr[j] = bf16b(p[j] * s);
            whh[nt][kc] = fr;
        }
#pragma unroll
        for (int kc = 0; kc < 2; ++kc) {
            const float* p = W_ih + g * 64 + kc * 32 + q * 8;
            bf16x8 fr;
#pragma unroll
            for (int j = 0; j < 8; ++j) fr[j] = bf16b(p[j] * s);
            wih[nt][kc] = fr;
        }
    }

    // ---- hoisted swizzled LDS offsets (loop-invariant) ----
    int hroff[4];                      // hbuf A-fragment reads (16B blocks)
#pragma unroll
    for (int kc = 0; kc < 4; ++kc)
        hroff[kc] = l15 * 128 + (((kc * 4 + q) ^ (l15 & 7)) << 3);
    int hwoff[4];                      // hbuf scalar h writes
#pragma unroll
    for (int j = 0; j < 4; ++j) {
        const int r = 4 * q + j;
        hwoff[j] = r * 128 + ((((u >> 3) ^ (r & 7))) << 3) + (u & 7);
    }
    int xroff[2];                      // sbuf A-fragment reads (within a step row-block)
#pragma unroll
    for (int kc = 0; kc < 2; ++kc)
        xroff[kc] = l15 * 64 + (((kc * 4 + q) ^ (l15 & 7)) << 3);

    // staging geometry: thread -> (batch row sr, step-in-chunk stt, 16-feat quad k4)
    const int sr  = tid >> 5;
    const int sub = tid & 31;
    const int stt = sub >> 2;
    const int k4  = sub & 3;
    const float* sbase = seq + ((size_t)(b0 + sr) * 1024 + stt) * 64 + k4 * 16;
    const int srow = stt * 16 + sr;
    const int ws0 = srow * 64 + (((2 * k4)     ^ (sr & 7)) << 3);
    const int ws1 = srow * 64 + (((2 * k4 + 1) ^ (sr & 7)) << 3);

    // zero initial h (t=0 reads hbuf[1])
    for (int i = tid; i < 16 * 128; i += 512) hbuf[1][i] = 0;

    // stage chunk 0
    {
        f32x4 ld[4];
#pragma unroll
        for (int i = 0; i < 4; ++i) ld[i] = ((const f32x4*)sbase)[i];
        st8(&sbuf[0][ws0], ld[0], ld[1]);
        st8(&sbuf[0][ws1], ld[2], ld[3]);
    }
    __syncthreads();

    float cc[4] = {0.f, 0.f, 0.f, 0.f};   // c for batch rows 4q+j, unit u
    float hl[4] = {0.f, 0.f, 0.f, 0.f};   // last h

    // prologue: x-projection accumulators for t=0
    f32x4 xacc[4];
    {
        const short* sb0 = sbuf[0];
        bf16x8 x0 = *(const bf16x8*)(sb0 + xroff[0]);
        bf16x8 x1 = *(const bf16x8*)(sb0 + xroff[1]);
#pragma unroll
        for (int nt = 0; nt < 4; ++nt) {
            f32x4 a = {bias[nt], bias[nt], bias[nt], bias[nt]};
            a = __builtin_amdgcn_mfma_f32_16x16x32_bf16(x0, wih[nt][0], a, 0, 0, 0);
            a = __builtin_amdgcn_mfma_f32_16x16x32_bf16(x1, wih[nt][1], a, 0, 0, 0);
            xacc[nt] = a;
        }
    }

#pragma unroll 1
    for (int ch = 0; ch < 128; ++ch) {
        f32x4 pend[4];
#pragma unroll
        for (int tt = 0; tt < 8; ++tt) {
            // issue next-chunk global loads early; LDS-write them at tt=4.
            // the lgkm-only barrier lets these stay in flight across steps.
            if (tt == 0 && ch + 1 < 128) {
                const float* p = sbase + (size_t)(ch + 1) * 512;
#pragma unroll
                for (int i = 0; i < 4; ++i) pend[i] = ((const f32x4*)p)[i];
            }

            // ---- h-GEMM for step t ----
            const short* hb = hbuf[(tt + 1) & 1];
            bf16x8 hA[4];
#pragma unroll
            for (int kc = 0; kc < 4; ++kc)
                hA[kc] = *(const bf16x8*)(hb + hroff[kc]);

            if (hiprio) __builtin_amdgcn_s_setprio(1);
            f32x4 gt[4];
#pragma unroll
            for (int nt = 0; nt < 4; ++nt) {
                f32x4 a = xacc[nt];
#pragma unroll
                for (int kc = 0; kc < 4; ++kc)
                    a = __builtin_amdgcn_mfma_f32_16x16x32_bf16(hA[kc], whh[nt][kc], a, 0, 0, 0);
                gt[nt] = a;
            }

            // ---- x-GEMM for step t+1 (independent of h(t)) ----
            if (tt < 7 || ch < 127) {
                const int tn   = ch * 8 + tt + 1;
                const short* sbn = sbuf[(tn >> 3) & 1];
                const int tb   = (tn & 7) * 1024;   // 16 rows * 64 shorts
                bf16x8 x0 = *(const bf16x8*)(sbn + tb + xroff[0]);
                bf16x8 x1 = *(const bf16x8*)(sbn + tb + xroff[1]);
#pragma unroll
                for (int nt = 0; nt < 4; ++nt) {
                    f32x4 a = {bias[nt], bias[nt], bias[nt], bias[nt]};
                    a = __builtin_amdgcn_mfma_f32_16x16x32_bf16(x0, wih[nt][0], a, 0, 0, 0);
                    a = __builtin_amdgcn_mfma_f32_16x16x32_bf16(x1, wih[nt][1], a, 0, 0, 0);
                    xacc[nt] = a;
                }
            }
            if (hiprio) __builtin_amdgcn_s_setprio(0);

            // LDS-write the prefetched chunk (4 steps of global latency hidden;
            // compiler inserts the vmcnt wait here, at the consumer)
            if (tt == 4 && ch + 1 < 128) {
                short* d = sbuf[(ch + 1) & 1];
                st8(d + ws0, pend[0], pend[1]);
                st8(d + ws1, pend[2], pend[3]);
            }

            // ---- elementwise: D row = 4q+j (batch), col = u (unit) ----
            // fused-rcp forms: i*g = (1-e_g)*rcp((1+e_g)(1+e_i));
            //                  o*tanh(c) = (1-e_c)*rcp((1+e_c)(1+e_o))
            short* hw = hbuf[tt & 1];
#pragma unroll
            for (int j = 0; j < 4; ++j) {
                float ei = fexp2(gt[0][j]);
                float ef = fexp2(gt[1][j]);
                float eg = fexp2(gt[2][j]);
                float eo = fexp2(gt[3][j]);
                float fg   = frcp(1.0f + ef);
                float igg  = (1.0f - eg) * frcp((1.0f + eg) * (1.0f + ei));
                float c    = __builtin_fmaf(fg, cc[j], igg);
                cc[j] = c;
                float ec = fexp2(c * NEG2L);
                hl[j] = (1.0f - ec) * frcp((1.0f + ec) * (1.0f + eo));
            }
            {
                unsigned int p01 = pk_bf16(hl[0], hl[1]);
                unsigned int p23 = pk_bf16(hl[2], hl[3]);
                hw[hwoff[0]] = (short)p01;
                hw[hwoff[1]] = (short)(p01 >> 16);
                hw[hwoff[2]] = (short)p23;
                hw[hwoff[3]] = (short)(p23 >> 16);
            }
            block_sync_lds();
        }
    }

    // ---- epilogue: tab branch + output head, fused per block ----
#pragma unroll
    for (int j = 0; j < 4; ++j) hff[4 * q + j][u] = hl[j];
    __syncthreads();

    {
        const int r   = tid >> 5;
        const int un0 = (tid & 31) * 4;
        const float* trow = tabular + (size_t)(b0 + r) * 128;
        float a0 = b_tab[un0], a1 = b_tab[un0 + 1], a2 = b_tab[un0 + 2], a3 = b_tab[un0 + 3];
        const float* w0 = W_tab + (un0 + 0) * 128;
        const float* w1 = W_tab + (un0 + 1) * 128;
        const float* w2 = W_tab + (un0 + 2) * 128;
        const float* w3 = W_tab + (un0 + 3) * 128;
#pragma unroll 4
        for (int f = 0; f < 128; f += 4) {
            f32x4 tv = *(const f32x4*)(trow + f);
            f32x4 v0 = *(const f32x4*)(w0 + f);
            f32x4 v1 = *(const f32x4*)(w1 + f);
            f32x4 v2 = *(const f32x4*)(w2 + f);
            f32x4 v3 = *(const f32x4*)(w3 + f);
#pragma unroll
            for (int e = 0; e < 4; ++e) {
                a0 += tv[e] * v0[e];
                a1 += tv[e] * v1[e];
                a2 += tv[e] * v2[e];
                a3 += tv[e] * v3[e];
            }
        }
        tbf[r][un0]     = fmaxf(a0, 0.f);
        tbf[r][un0 + 1] = fmaxf(a1, 0.f);
        tbf[r][un0 + 2] = fmaxf(a2, 0.f);
        tbf[r][un0 + 3] = fmaxf(a3, 0.f);
    }
    __syncthreads();

    if (tid < 32) {
        const int r = tid >> 1, o = tid & 1;
        const float* w = W_out + o * 256;
        float a = b_out[o];
#pragma unroll 8
        for (int j = 0; j < 128; ++j) a += hff[r][j] * w[j];
#pragma unroll 8
        for (int j = 0; j < 128; ++j) a += tbf[r][j] * w[128 + j];
        out[(size_t)(b0 + r) * 2 + o] = a;
    }
}

extern "C" void kernel_launch(void* const* d_in, const int* in_sizes, int n_in,
                              void* d_out, int out_size, void* d_ws, size_t ws_size,
                              hipStream_t stream) {
    const float* tabular = (const float*)d_in[0];
    const float* seq     = (const float*)d_in[1];
    const float* W_ih    = (const float*)d_in[2];
    const float* W_hh    = (const float*)d_in[3];
    const float* b_ih    = (const float*)d_in[4];
    const float* b_hh    = (const float*)d_in[5];
    const float* W_tab   = (const float*)d_in[6];
    const float* b_tab   = (const float*)d_in[7];
    const float* W_out   = (const float*)d_in[8];
    const float* b_out   = (const float*)d_in[9];
    float* o = (float*)d_out;
    hipLaunchKernelGGL(lstm_fused, dim3(32), dim3(512), 0, stream,
                       tabular, seq, W_ih, W_hh, b_ih, b_hh, W_tab, b_tab, W_out, b_out, o);
}

// Round 7
// 989.186 us; speedup vs baseline: 1.0267x; 1.0267x over previous
//
#include <hip/hip_runtime.h>
#include <hip/hip_bf16.h>

// B=512, T=1024, F_SEQ=64, F_TAB=128, H_SEQ=128, H_TAB=128
// 32 persistent blocks (16 batch rows each), 512 threads (8 waves).
// Wave w owns hidden units [16w,16w+16) and their 4 gate tiles (i,f,g,o).
// Weights in registers as bf16 MFMA B-fragments pre-scaled by -log2e
// (g gate by -2log2e) so sigmoid/tanh = rcp(1+exp2(y)) with no negation.
// h double-buffered in LDS (bf16, XOR-swizzled 16B blocks, no padding);
// seq staged 8 steps ahead (bf16, swizzled, packed cvt). c in fp32 regs.
// R2-R5 measured MfmaUtil+VALUBusy ~= 93% serialized; setprio (symmetric
// and parity-staggered) did nothing. This round: NO setprio — the intrinsic
// is a compiler scheduling fence that trapped the independent work
// (x-GEMM(t+1), staging) inside the MFMA cluster and kept the elementwise
// outside it. With fences gone the scheduler can interleave elementwise(t)
// VALU with x-GEMM(t+1) MFMAs and staging, overlapping the two pipes.
// Bias splat hoisted out of the loop and fed as MFMA C-operand directly.
// Main-loop sync is lgkmcnt-only raw s_barrier: __syncthreads would drain
// vmcnt(0) and expose the seq-prefetch HBM latency at the tt=0 barrier.
// Elementwise uses fused rcp algebra: i*g and o*tanh(c) each need one rcp.

typedef __attribute__((ext_vector_type(8))) short bf16x8;
typedef __attribute__((ext_vector_type(4))) float f32x4;
typedef __attribute__((ext_vector_type(4))) unsigned int u32x4;

#define LOG2E 1.44269504088896340736f
#define NEG2L (-2.0f * LOG2E)

__device__ __forceinline__ float fexp2(float x) {
#if __has_builtin(__builtin_amdgcn_exp2f)
    return __builtin_amdgcn_exp2f(x);
#else
    float r; asm("v_exp_f32 %0, %1" : "=v"(r) : "v"(x)); return r;
#endif
}
__device__ __forceinline__ float frcp(float x) {
#if __has_builtin(__builtin_amdgcn_rcpf)
    return __builtin_amdgcn_rcpf(x);
#else
    float r; asm("v_rcp_f32 %0, %1" : "=v"(r) : "v"(x)); return r;
#endif
}

__device__ __forceinline__ unsigned int pk_bf16(float a, float b) {
    float2 f2; f2.x = a; f2.y = b;
    __hip_bfloat162 h = __float22bfloat162_rn(f2);
    unsigned int r; __builtin_memcpy(&r, &h, 4); return r;
}
__device__ __forceinline__ short bf16b(float x) {
    __hip_bfloat16 h = __float2bfloat16(x);
    short r; __builtin_memcpy(&r, &h, 2); return r;
}

// convert 8 fp32 -> 8 bf16 and store 16B to LDS (dst 16B-aligned)
__device__ __forceinline__ void st8(short* dst, const f32x4 a, const f32x4 b) {
    u32x4 v = { pk_bf16(a[0], a[1]), pk_bf16(a[2], a[3]),
                pk_bf16(b[0], b[1]), pk_bf16(b[2], b[3]) };
    *(u32x4*)dst = v;
}

// lgkm-only block barrier: drains own LDS ops (visibility) but leaves
// global loads in flight across the barrier (no vmcnt(0) drain).
__device__ __forceinline__ void block_sync_lds() {
    asm volatile("s_waitcnt lgkmcnt(0)" ::: "memory");
    __builtin_amdgcn_s_barrier();
}

__global__ __launch_bounds__(512, 2)
void lstm_fused(const float* __restrict__ tabular,
                const float* __restrict__ seq,
                const float* __restrict__ W_ih,
                const float* __restrict__ W_hh,
                const float* __restrict__ b_ih,
                const float* __restrict__ b_hh,
                const float* __restrict__ W_tab,
                const float* __restrict__ b_tab,
                const float* __restrict__ W_out,
                const float* __restrict__ b_out,
                float* __restrict__ out)
{
    // swizzled layouts: addr(row,col) = row*STRIDE + ((col>>3 ^ (row&7))<<3) + (col&7)
    __shared__ short hbuf[2][16 * 128];      // h double buffer (bf16)
    __shared__ short sbuf[2][8 * 16 * 64];   // seq chunk double buffer (bf16)
    __shared__ float hff[16][132];           // final h (fp32)
    __shared__ float tbf[16][132];           // tab branch (fp32)

    const int tid  = threadIdx.x;
    const int lane = tid & 63;
    const int wid  = tid >> 6;       // wave 0..7
    const int l15  = lane & 15;
    const int q    = lane >> 4;      // 0..3
    const int b0   = blockIdx.x * 16;
    const int u    = wid * 16 + l15; // hidden unit 0..127

    // ---- weight fragments (bf16, pre-scaled by -s) ----
    // gate tile nt: 0=i 1=f 2=g 3=o ; gate row = nt*128 + u
    bf16x8 whh[4][4];
    bf16x8 wih[4][2];
    f32x4  biasv[4];                 // splat once; used as MFMA C-in each step
#pragma unroll
    for (int nt = 0; nt < 4; ++nt) {
        const int g = nt * 128 + u;
        const float s = (nt == 2) ? (-2.0f * LOG2E) : (-LOG2E);
        const float b = (b_ih[g] + b_hh[g]) * s;
        biasv[nt] = (f32x4){b, b, b, b};
#pragma unroll
        for (int kc = 0; kc < 4; ++kc) {
            const float* p = W_hh + g * 128 + kc * 32 + q * 8;
            bf16x8 fr;
#pragma unroll
            for (int j = 0; j < 8; ++j) fr[j] = bf16b(p[j] * s);
            whh[nt][kc] = fr;
        }
#pragma unroll
        for (int kc = 0; kc < 2; ++kc) {
            const float* p = W_ih + g * 64 + kc * 32 + q * 8;
            bf16x8 fr;
#pragma unroll
            for (int j = 0; j < 8; ++j) fr[j] = bf16b(p[j] * s);
            wih[nt][kc] = fr;
        }
    }

    // ---- hoisted swizzled LDS offsets (loop-invariant) ----
    int hroff[4];                      // hbuf A-fragment reads (16B blocks)
#pragma unroll
    for (int kc = 0; kc < 4; ++kc)
        hroff[kc] = l15 * 128 + (((kc * 4 + q) ^ (l15 & 7)) << 3);
    int hwoff[4];                      // hbuf scalar h writes
#pragma unroll
    for (int j = 0; j < 4; ++j) {
        const int r = 4 * q + j;
        hwoff[j] = r * 128 + ((((u >> 3) ^ (r & 7))) << 3) + (u & 7);
    }
    int xroff[2];                      // sbuf A-fragment reads (within a step row-block)
#pragma unroll
    for (int kc = 0; kc < 2; ++kc)
        xroff[kc] = l15 * 64 + (((kc * 4 + q) ^ (l15 & 7)) << 3);

    // staging geometry: thread -> (batch row sr, step-in-chunk stt, 16-feat quad k4)
    const int sr  = tid >> 5;
    const int sub = tid & 31;
    const int stt = sub >> 2;
    const int k4  = sub & 3;
    const float* sbase = seq + ((size_t)(b0 + sr) * 1024 + stt) * 64 + k4 * 16;
    const int srow = stt * 16 + sr;
    const int ws0 = srow * 64 + (((2 * k4)     ^ (sr & 7)) << 3);
    const int ws1 = srow * 64 + (((2 * k4 + 1) ^ (sr & 7)) << 3);

    // zero initial h (t=0 reads hbuf[1])
    for (int i = tid; i < 16 * 128; i += 512) hbuf[1][i] = 0;

    // stage chunk 0
    {
        f32x4 ld[4];
#pragma unroll
        for (int i = 0; i < 4; ++i) ld[i] = ((const f32x4*)sbase)[i];
        st8(&sbuf[0][ws0], ld[0], ld[1]);
        st8(&sbuf[0][ws1], ld[2], ld[3]);
    }
    __syncthreads();

    float cc[4] = {0.f, 0.f, 0.f, 0.f};   // c for batch rows 4q+j, unit u
    float hl[4] = {0.f, 0.f, 0.f, 0.f};   // last h

    // prologue: x-projection accumulators for t=0
    f32x4 xacc[4];
    {
        const short* sb0 = sbuf[0];
        bf16x8 x0 = *(const bf16x8*)(sb0 + xroff[0]);
        bf16x8 x1 = *(const bf16x8*)(sb0 + xroff[1]);
#pragma unroll
        for (int nt = 0; nt < 4; ++nt) {
            f32x4 a = __builtin_amdgcn_mfma_f32_16x16x32_bf16(x0, wih[nt][0], biasv[nt], 0, 0, 0);
            xacc[nt] = __builtin_amdgcn_mfma_f32_16x16x32_bf16(x1, wih[nt][1], a, 0, 0, 0);
        }
    }

#pragma unroll 1
    for (int ch = 0; ch < 128; ++ch) {
        f32x4 pend[4];
#pragma unroll
        for (int tt = 0; tt < 8; ++tt) {
            // issue next-chunk global loads early; LDS-write them at tt=4.
            // the lgkm-only barrier lets these stay in flight across steps.
            if (tt == 0 && ch + 1 < 128) {
                const float* p = sbase + (size_t)(ch + 1) * 512;
#pragma unroll
                for (int i = 0; i < 4; ++i) pend[i] = ((const f32x4*)p)[i];
            }

            // ---- h-GEMM for step t ----
            const short* hb = hbuf[(tt + 1) & 1];
            bf16x8 hA[4];
#pragma unroll
            for (int kc = 0; kc < 4; ++kc)
                hA[kc] = *(const bf16x8*)(hb + hroff[kc]);

            f32x4 gt[4];
#pragma unroll
            for (int nt = 0; nt < 4; ++nt) {
                f32x4 a = xacc[nt];
#pragma unroll
                for (int kc = 0; kc < 4; ++kc)
                    a = __builtin_amdgcn_mfma_f32_16x16x32_bf16(hA[kc], whh[nt][kc], a, 0, 0, 0);
                gt[nt] = a;
            }

            // ---- x-GEMM for step t+1 (independent of gt; free to interleave
            // with the elementwise below — no fences in between) ----
            if (tt < 7 || ch < 127) {
                const int tn   = ch * 8 + tt + 1;
                const short* sbn = sbuf[(tn >> 3) & 1];
                const int tb   = (tn & 7) * 1024;   // 16 rows * 64 shorts
                bf16x8 x0 = *(const bf16x8*)(sbn + tb + xroff[0]);
                bf16x8 x1 = *(const bf16x8*)(sbn + tb + xroff[1]);
#pragma unroll
                for (int nt = 0; nt < 4; ++nt) {
                    f32x4 a = __builtin_amdgcn_mfma_f32_16x16x32_bf16(x0, wih[nt][0], biasv[nt], 0, 0, 0);
                    xacc[nt] = __builtin_amdgcn_mfma_f32_16x16x32_bf16(x1, wih[nt][1], a, 0, 0, 0);
                }
            }

            // LDS-write the prefetched chunk (4 steps of global latency hidden;
            // compiler inserts the vmcnt wait here, at the consumer)
            if (tt == 4 && ch + 1 < 128) {
                short* d = sbuf[(ch + 1) & 1];
                st8(d + ws0, pend[0], pend[1]);
                st8(d + ws1, pend[2], pend[3]);
            }

            // ---- elementwise: D row = 4q+j (batch), col = u (unit) ----
            // fused-rcp forms: i*g = (1-e_g)*rcp((1+e_g)(1+e_i));
            //                  o*tanh(c) = (1-e_c)*rcp((1+e_c)(1+e_o))
            short* hw = hbuf[tt & 1];
#pragma unroll
            for (int j = 0; j < 4; ++j) {
                float ei = fexp2(gt[0][j]);
                float ef = fexp2(gt[1][j]);
                float eg = fexp2(gt[2][j]);
                float eo = fexp2(gt[3][j]);
                float fg   = frcp(1.0f + ef);
                float igg  = (1.0f - eg) * frcp((1.0f + eg) * (1.0f + ei));
                float c    = __builtin_fmaf(fg, cc[j], igg);
                cc[j] = c;
                float ec = fexp2(c * NEG2L);
                hl[j] = (1.0f - ec) * frcp((1.0f + ec) * (1.0f + eo));
            }
            {
                unsigned int p01 = pk_bf16(hl[0], hl[1]);
                unsigned int p23 = pk_bf16(hl[2], hl[3]);
                hw[hwoff[0]] = (short)p01;
                hw[hwoff[1]] = (short)(p01 >> 16);
                hw[hwoff[2]] = (short)p23;
                hw[hwoff[3]] = (short)(p23 >> 16);
            }
            block_sync_lds();
        }
    }

    // ---- epilogue: tab branch + output head, fused per block ----
#pragma unroll
    for (int j = 0; j < 4; ++j) hff[4 * q + j][u] = hl[j];
    __syncthreads();

    {
        const int r   = tid >> 5;
        const int un0 = (tid & 31) * 4;
        const float* trow = tabular + (size_t)(b0 + r) * 128;
        float a0 = b_tab[un0], a1 = b_tab[un0 + 1], a2 = b_tab[un0 + 2], a3 = b_tab[un0 + 3];
        const float* w0 = W_tab + (un0 + 0) * 128;
        const float* w1 = W_tab + (un0 + 1) * 128;
        const float* w2 = W_tab + (un0 + 2) * 128;
        const float* w3 = W_tab + (un0 + 3) * 128;
#pragma unroll 4
        for (int f = 0; f < 128; f += 4) {
            f32x4 tv = *(const f32x4*)(trow + f);
            f32x4 v0 = *(const f32x4*)(w0 + f);
            f32x4 v1 = *(const f32x4*)(w1 + f);
            f32x4 v2 = *(const f32x4*)(w2 + f);
            f32x4 v3 = *(const f32x4*)(w3 + f);
#pragma unroll
            for (int e = 0; e < 4; ++e) {
                a0 += tv[e] * v0[e];
                a1 += tv[e] * v1[e];
                a2 += tv[e] * v2[e];
                a3 += tv[e] * v3[e];
            }
        }
        tbf[r][un0]     = fmaxf(a0, 0.f);
        tbf[r][un0 + 1] = fmaxf(a1, 0.f);
        tbf[r][un0 + 2] = fmaxf(a2, 0.f);
        tbf[r][un0 + 3] = fmaxf(a3, 0.f);
    }
    __syncthreads();

    if (tid < 32) {
        const int r = tid >> 1, o = tid & 1;
        const float* w = W_out + o * 256;
        float a = b_out[o];
#pragma unroll 8
        for (int j = 0; j < 128; ++j) a += hff[r][j] * w[j];
#pragma unroll 8
        for (int j = 0; j < 128; ++j) a += tbf[r][j] * w[128 + j];
        out[(size_t)(b0 + r) * 2 + o] = a;
    }
}

extern "C" void kernel_launch(void* const* d_in, const int* in_sizes, int n_in,
                              void* d_out, int out_size, void* d_ws, size_t ws_size,
                              hipStream_t stream) {
    const float* tabular = (const float*)d_in[0];
    const float* seq     = (const float*)d_in[1];
    const float* W_ih    = (const float*)d_in[2];
    const float* W_hh    = (const float*)d_in[3];
    const float* b_ih    = (const float*)d_in[4];
    const float* b_hh    = (const float*)d_in[5];
    const float* W_tab   = (const float*)d_in[6];
    const float* b_tab   = (const float*)d_in[7];
    const float* W_out   = (const float*)d_in[8];
    const float* b_out   = (const float*)d_in[9];
    float* o = (float*)d_out;
    hipLaunchKernelGGL(lstm_fused, dim3(32), dim3(512), 0, stream,
                       tabular, seq, W_ih, W_hh, b_ih, b_hh, W_tab, b_tab, W_out, b_out, o);
}